// Round 3
// baseline (1098.410 us; speedup 1.0000x reference)
//
#include <hip/hip_runtime.h>
#include <hip/hip_bf16.h>

#define Lv 1024
#define Vv 96
#define Ev 64
#define Hv 256
#define ROWS 16
#define HOFF (256 * 1024 * 96)
#define HBUF 4096  // ushorts per h buffer

typedef __attribute__((ext_vector_type(8))) short bf16x8;
typedef __attribute__((ext_vector_type(4))) float f32x4;
typedef __attribute__((ext_vector_type(2))) unsigned int u32x2;
typedef __attribute__((ext_vector_type(4))) unsigned int u32x4;

__device__ __forceinline__ unsigned short f2b(float f) {
  unsigned u = __builtin_bit_cast(unsigned, f);
  return (unsigned short)((u + 0x7fffu + ((u >> 16) & 1u)) >> 16);  // RNE
}
__device__ __forceinline__ unsigned cvtpk_bf16(float lo, float hi) {
  unsigned r;
  asm("v_cvt_pk_bf16_f32 %0, %1, %2" : "=v"(r) : "v"(lo), "v"(hi));
  return r;
}
__device__ __forceinline__ bf16x8 pack8(f32x4 a, f32x4 b) {
  u32x4 t;
  t[0] = cvtpk_bf16(a[0], a[1]);
  t[1] = cvtpk_bf16(a[2], a[3]);
  t[2] = cvtpk_bf16(b[0], b[1]);
  t[3] = cvtpk_bf16(b[2], b[3]);
  return __builtin_bit_cast(bf16x8, t);
}
__device__ __forceinline__ float fast_tanh(float x) {
  float e = __builtin_amdgcn_exp2f(x * 2.885390081777927f);  // exp(2x)
  return 1.0f - 2.0f * __builtin_amdgcn_rcpf(e + 1.0f);
}
// One barrier per step: wait LDS ops only; global stores/loads keep draining.
__device__ __forceinline__ void step_barrier() {
  asm volatile("s_waitcnt lgkmcnt(0)\n\ts_barrier" ::: "memory");
  __builtin_amdgcn_sched_barrier(0);
}

__global__ void detect_i64(const int* __restrict__ x, int* __restrict__ flag) {
  if (threadIdx.x == 0 && blockIdx.x == 0) {
    int ok = 1;
    for (int i = 0; i < 64; ++i) ok &= (x[2 * i + 1] == 0);
    *flag = ok;
  }
}

// Transposed recurrence: h_t^T[j,b] = tanh(Wh[.,j]·h^T + Wx[.,j]·emb^T + b).
// 16 WGs x 16 batch cols, 4 waves; wave w owns hidden rows [64w,64w+64) (A =
// weights in regs) and logits v-tiles (2,2,1,1 split of 6). h^T in swizzled
// LDS (16B-chunk XOR), double-buffered, 1 lgkm-only barrier/step.
__global__ __launch_bounds__(256, 1) void rnn_fused(
    const int* __restrict__ x, const float* __restrict__ h0,
    const float* __restrict__ emb, const float* __restrict__ W_ih,
    const float* __restrict__ b_ih, const float* __restrict__ W_ho,
    const float* __restrict__ b_ho, float* __restrict__ out,
    const int* __restrict__ flagp) {
  const int tid = threadIdx.x;
  const int w = tid >> 6, ln = tid & 63, lm = ln & 15, g = ln >> 4;
  const int r0 = blockIdx.x * ROWS;

  __shared__ __attribute__((aligned(16))) unsigned short s_h[2 * HBUF];

  // stage h_{-1} into buf1 (swizzled: chunk = hidden>>3, chunk ^= batch&7)
  for (int idx = tid; idx < ROWS * Hv; idx += 256) {
    int b_ = idx >> 8, hd = idx & 255;
    s_h[HBUF + b_ * 256 + ((((hd >> 3) ^ (b_ & 7)) << 3) | (hd & 7))] =
        f2b(h0[(r0 + b_) * Hv + hd]);
  }

  // ---- register-resident weights (A-fragments: row=lm, k=8g+i) ----
  bf16x8 wh[4][8], wx[4][2], who[2][8];
  f32x4 bihv[4], bhv[2];
#pragma unroll
  for (int nt = 0; nt < 4; ++nt) {
    const int n = 64 * w + 16 * nt + lm;  // output hidden row
#pragma unroll
    for (int kf = 0; kf < 8; ++kf)
#pragma unroll
      for (int i = 0; i < 8; ++i)
        wh[nt][kf][i] = (short)f2b(W_ih[(Ev + 32 * kf + 8 * g + i) * Hv + n]);
#pragma unroll
    for (int kf = 0; kf < 2; ++kf)
#pragma unroll
      for (int i = 0; i < 8; ++i)
        wx[nt][kf][i] = (short)f2b(W_ih[(32 * kf + 8 * g + i) * Hv + n]);
    bihv[nt] = *(const f32x4*)&b_ih[64 * w + 16 * nt + 4 * g];
  }
  const int njt = (w < 2) ? 2 : 1;
  const int jtb = (w < 2) ? 2 * w : (w + 2);  // v-tiles: {0,1},{2,3},{4},{5}
#pragma unroll
  for (int j = 0; j < 2; ++j)
    if (j < njt) {
      const int nv = 16 * (jtb + j) + lm;  // output v row
#pragma unroll
      for (int kf = 0; kf < 8; ++kf)
#pragma unroll
        for (int i = 0; i < 8; ++i)
          who[j][kf][i] = (short)f2b(W_ho[(32 * kf + 8 * g + i) * Vv + nv]);
      bhv[j] = *(const f32x4*)&b_ho[16 * (jtb + j) + 4 * g];
    }

  // ---- loop-invariant addresses ----
  const unsigned short* ra[8];
#pragma unroll
  for (int kf = 0; kf < 8; ++kf)
    ra[kf] = &s_h[lm * 256 + (((4 * kf + g) ^ (lm & 7)) << 3)];
  unsigned short* wa[4];
#pragma unroll
  for (int nt = 0; nt < 4; ++nt)
    wa[nt] = &s_h[lm * 256 + (((8 * w + 2 * nt + (g >> 1)) ^ (lm & 7)) << 3) +
                  ((g & 1) << 2)];
  float* lptr[2] = {out, out};
#pragma unroll
  for (int j = 0; j < 2; ++j)
    if (j < njt)
      lptr[j] = out + (size_t)(r0 + lm) * (Lv * Vv) + 16 * (jtb + j) + 4 * g;

  const int flag = *flagp;  // 1 => x is int64
  const long long xoff = (long long)(r0 + lm) * Lv;
  const int* xp = x + (flag ? 2 * xoff : xoff);
  const int xstr = flag ? 2 : 1;

  __syncthreads();

  // prime: pe = emb rows for t=0 (fp32), xi_n = x[1]
  f32x4 pe0, pe1, pe2, pe3;
  int xi_n;
  {
    int xi0 = xp[0];
    xi_n = xp[xstr];
    const float* ep = &emb[xi0 * Ev + 8 * g];
    pe0 = *(const f32x4*)ep;
    pe1 = *(const f32x4*)(ep + 4);
    pe2 = *(const f32x4*)(ep + 32);
    pe3 = *(const f32x4*)(ep + 36);
  }

#define STEP(TT, RB, WB, DOLOG, LAST)                                             \
  do {                                                                            \
    bf16x8 ef0 = pack8(pe0, pe1), ef1 = pack8(pe2, pe3);                          \
    bf16x8 af[8];                                                                 \
    _Pragma("unroll") for (int kf = 0; kf < 8; ++kf)                              \
        af[kf] = *(const bf16x8*)(ra[kf] + (RB));                                 \
    f32x4 aA[4], aB[4];                                                           \
    _Pragma("unroll") for (int nt = 0; nt < 4; ++nt) {                            \
      aA[nt] = bihv[nt];                                                          \
      aB[nt] = (f32x4){0.f, 0.f, 0.f, 0.f};                                       \
    }                                                                             \
    _Pragma("unroll") for (int kf = 0; kf < 4; ++kf)                              \
        _Pragma("unroll") for (int nt = 0; nt < 4; ++nt)                          \
        aA[nt] = __builtin_amdgcn_mfma_f32_16x16x32_bf16(wh[nt][kf], af[kf],      \
                                                         aA[nt], 0, 0, 0);        \
    _Pragma("unroll") for (int kf = 4; kf < 8; ++kf)                              \
        _Pragma("unroll") for (int nt = 0; nt < 4; ++nt)                          \
        aB[nt] = __builtin_amdgcn_mfma_f32_16x16x32_bf16(wh[nt][kf], af[kf],      \
                                                         aB[nt], 0, 0, 0);        \
    if (DOLOG) {                                                                  \
      _Pragma("unroll") for (int j = 0; j < 2; ++j) if (j < njt) {                \
        f32x4 l = bhv[j];                                                         \
        _Pragma("unroll") for (int kf = 0; kf < 8; ++kf)                          \
            l = __builtin_amdgcn_mfma_f32_16x16x32_bf16(who[j][kf], af[kf], l,    \
                                                        0, 0, 0);                 \
        *(f32x4*)lptr[j] = l;                                                     \
        lptr[j] += Vv;                                                            \
      }                                                                           \
    }                                                                             \
    { /* prefetch emb for TT+1, x for TT+2 */                                     \
      const float* ep = &emb[xi_n * Ev + 8 * g];                                  \
      pe0 = *(const f32x4*)ep;                                                    \
      pe1 = *(const f32x4*)(ep + 4);                                              \
      pe2 = *(const f32x4*)(ep + 32);                                             \
      pe3 = *(const f32x4*)(ep + 36);                                             \
      int tn = ((TT) + 2 < Lv) ? (TT) + 2 : (Lv - 1);                             \
      xi_n = xp[tn * xstr];                                                       \
    }                                                                             \
    _Pragma("unroll") for (int nt = 0; nt < 4; ++nt)                              \
        aA[nt] = __builtin_amdgcn_mfma_f32_16x16x32_bf16(wx[nt][0], ef0, aA[nt],  \
                                                         0, 0, 0);                \
    _Pragma("unroll") for (int nt = 0; nt < 4; ++nt)                              \
        aB[nt] = __builtin_amdgcn_mfma_f32_16x16x32_bf16(wx[nt][1], ef1, aB[nt],  \
                                                         0, 0, 0);                \
    _Pragma("unroll") for (int nt = 0; nt < 4; ++nt) {                            \
      f32x4 hv;                                                                   \
      _Pragma("unroll") for (int rr = 0; rr < 4; ++rr)                            \
          hv[rr] = fast_tanh(aA[nt][rr] + aB[nt][rr]);                            \
      u32x2 p;                                                                    \
      p[0] = cvtpk_bf16(hv[0], hv[1]);                                            \
      p[1] = cvtpk_bf16(hv[2], hv[3]);                                            \
      *(u32x2*)(wa[nt] + (WB)) = p;                                               \
      if (LAST)                                                                   \
        *(f32x4*)(out + HOFF + (size_t)(r0 + lm) * Hv + 64 * w + 16 * nt +        \
                  4 * g) = hv;                                                    \
    }                                                                             \
    step_barrier();                                                               \
  } while (0)

  STEP(0, HBUF, 0, 0, 0);  // h_{-1} in buf1 -> h_0 in buf0
  for (int t = 1; t < Lv - 1; t += 2) {
    STEP(t, 0, HBUF, 1, 0);
    STEP(t + 1, HBUF, 0, 1, 0);
  }
  STEP(Lv - 1, 0, HBUF, 1, 1);  // logits t=1022, h_1023 -> buf1, final hidden

  // epilogue: logits for t = Lv-1 from h_1023 (buf1)
  {
    bf16x8 af[8];
#pragma unroll
    for (int kf = 0; kf < 8; ++kf) af[kf] = *(const bf16x8*)(ra[kf] + HBUF);
#pragma unroll
    for (int j = 0; j < 2; ++j)
      if (j < njt) {
        f32x4 l = bhv[j];
#pragma unroll
        for (int kf = 0; kf < 8; ++kf)
          l = __builtin_amdgcn_mfma_f32_16x16x32_bf16(who[j][kf], af[kf], l, 0,
                                                      0, 0);
        *(f32x4*)lptr[j] = l;
      }
  }
#undef STEP
}

extern "C" void kernel_launch(void* const* d_in, const int* in_sizes, int n_in,
                              void* d_out, int out_size, void* d_ws, size_t ws_size,
                              hipStream_t stream) {
  const int* x     = (const int*)d_in[0];
  const float* h0  = (const float*)d_in[1];
  const float* emb = (const float*)d_in[2];
  const float* Wih = (const float*)d_in[3];
  const float* bih = (const float*)d_in[4];
  const float* Who = (const float*)d_in[5];
  const float* bho = (const float*)d_in[6];
  float* out = (float*)d_out;
  int* flag = (int*)d_ws;

  detect_i64<<<1, 64, 0, stream>>>(x, flag);
  rnn_fused<<<16, 256, 0, stream>>>(x, h0, emb, Wih, bih, Who, bho, out, flag);
}

// Round 4
// 891.425 us; speedup vs baseline: 1.2322x; 1.2322x over previous
//
#include <hip/hip_runtime.h>
#include <hip/hip_bf16.h>

#define Lv 1024
#define Vv 96
#define Ev 64
#define Hv 256
#define ROWS 16
#define HOFF (256 * 1024 * 96)
#define EPAD 72
#define HB 4096  // ushorts per h buffer (16 rows x 256)

typedef __attribute__((ext_vector_type(8))) short bf16x8;
typedef __attribute__((ext_vector_type(4))) float f32x4;
typedef __attribute__((ext_vector_type(2))) unsigned int u32x2;

__device__ __forceinline__ unsigned short f2b(float f) {
  unsigned u = __builtin_bit_cast(unsigned, f);
  return (unsigned short)((u + 0x7fffu + ((u >> 16) & 1u)) >> 16);  // RNE
}
__device__ __forceinline__ unsigned cvtpk_bf16(float lo, float hi) {
  unsigned r;
  asm("v_cvt_pk_bf16_f32 %0, %1, %2" : "=v"(r) : "v"(lo), "v"(hi));
  return r;
}
__device__ __forceinline__ float fast_tanh(float x) {
  float e = __builtin_amdgcn_exp2f(x * 2.885390081777927f);  // exp(2x)
  return 1.0f - 2.0f * __builtin_amdgcn_rcpf(e + 1.0f);
}
// lgkm-only barrier: LDS ordered, global stores keep draining across steps.
__device__ __forceinline__ void step_barrier() {
  asm volatile("s_waitcnt lgkmcnt(0)\n\ts_barrier" ::: "memory");
  __builtin_amdgcn_sched_barrier(0);
}

__global__ void detect_i64(const int* __restrict__ x, int* __restrict__ flag) {
  if (threadIdx.x == 0 && blockIdx.x == 0) {
    int ok = 1;
    for (int i = 0; i < 64; ++i) ok &= (x[2 * i + 1] == 0);
    *flag = ok;
  }
}

// ============================ primary path =============================
// 16 WGs x 16 batch rows, 16 waves (1024 thr, <=128 VGPR -> 4 waves/SIMD).
// Wave w owns hidden cols [16w,16w+16). No logits in loop; h_t exported to
// hs[t][b][h] (bf16) for a deferred full-chip logits GEMM.
__global__ __launch_bounds__(1024, 1) void rnn16(
    const int* __restrict__ x, const float* __restrict__ h0,
    const float* __restrict__ emb, const float* __restrict__ W_ih,
    const float* __restrict__ b_ih, float* __restrict__ out,
    unsigned short* __restrict__ hs, const int* __restrict__ flagp) {
  const int tid = threadIdx.x;
  const int w = tid >> 6, ln = tid & 63, lm = ln & 15, g = ln >> 4;
  const int r0 = blockIdx.x * ROWS;

  __shared__ __attribute__((aligned(16))) unsigned short s_h[2 * HB];
  __shared__ __attribute__((aligned(16))) unsigned short s_emb[Vv * EPAD];
  __shared__ unsigned char s_x[Lv * ROWS];

  const int flag = *flagp;  // 1 => x is int64

  for (int idx = tid; idx < Vv * Ev; idx += 1024)
    s_emb[(idx >> 6) * EPAD + (idx & 63)] = f2b(emb[idx]);
  for (int idx = tid; idx < ROWS * Hv; idx += 1024) {  // h_{-1} -> buf1
    int b_ = idx >> 8, hd = idx & 255;
    s_h[HB + b_ * 256 + ((((hd >> 3) ^ (b_ & 7)) << 3) | (hd & 7))] =
        f2b(h0[(r0 + b_) * Hv + hd]);
  }
  for (int idx = tid; idx < ROWS * Lv; idx += 1024) {  // x, transposed u8
    int t = idx >> 4, row = idx & 15;
    long long src = (long long)(r0 + row) * Lv + t;
    int v = flag ? x[2 * src] : x[src];
    s_x[t * ROWS + row] = (unsigned char)v;
  }

  // weights: wave w covers hidden col n = 16w+lm (B-frags, k=8g+i)
  bf16x8 wh[8], wx[2];
  const int n = 16 * w + lm;
#pragma unroll
  for (int kf = 0; kf < 8; ++kf)
#pragma unroll
    for (int i = 0; i < 8; ++i)
      wh[kf][i] = (short)f2b(W_ih[(Ev + 32 * kf + 8 * g + i) * Hv + n]);
#pragma unroll
  for (int kf = 0; kf < 2; ++kf)
#pragma unroll
    for (int i = 0; i < 8; ++i)
      wx[kf][i] = (short)f2b(W_ih[(32 * kf + 8 * g + i) * Hv + n]);
  const float bih = b_ih[n];

  // loop-invariant LDS element offsets
  const unsigned short* ra[8];
#pragma unroll
  for (int kf = 0; kf < 8; ++kf)
    ra[kf] = &s_h[lm * 256 + (((4 * kf + g) ^ (lm & 7)) << 3)];
  unsigned short* wa[4];
#pragma unroll
  for (int rr = 0; rr < 4; ++rr) {
    int b_ = 4 * g + rr;
    wa[rr] = &s_h[b_ * 256 + ((((2 * w + (lm >> 3)) ^ (b_ & 7)) << 3) | (lm & 7))];
  }
  // export: wave w exports batch row w; lane ln covers h = 4*ln..4*ln+3
  const unsigned short* ea =
      &s_h[w * 256 + ((((ln >> 1) ^ (w & 7)) << 3) | ((ln & 1) << 2))];
  unsigned short* hp = hs + (size_t)(r0 + w) * 256 + ln * 4;  // t=0 slot

  __syncthreads();

  bf16x8 ef0, ef1;
  int xi_n;
  {
    int xi0 = s_x[lm];
    const unsigned short* ep = &s_emb[xi0 * EPAD + 8 * g];
    ef0 = *(const bf16x8*)ep;
    ef1 = *(const bf16x8*)(ep + 32);
    xi_n = s_x[ROWS + lm];  // t=1
  }

#define STEP(TT, RBe, WBe, EXPORT, LAST)                                          \
  do {                                                                            \
    if (EXPORT) { /* h_{TT-1} from read buffer -> hs[TT-1] */                     \
      u32x2 ev = *(const u32x2*)(ea + (RBe));                                     \
      *(u32x2*)hp = ev;                                                           \
      hp += (size_t)Hv * 256;                                                     \
    }                                                                             \
    bf16x8 af[8];                                                                 \
    _Pragma("unroll") for (int kf = 0; kf < 8; ++kf)                              \
        af[kf] = *(const bf16x8*)(ra[kf] + (RBe));                                \
    f32x4 aA = {bih, bih, bih, bih};                                              \
    f32x4 aB = {0.f, 0.f, 0.f, 0.f};                                              \
    aA = __builtin_amdgcn_mfma_f32_16x16x32_bf16(ef0, wx[0], aA, 0, 0, 0);        \
    aB = __builtin_amdgcn_mfma_f32_16x16x32_bf16(ef1, wx[1], aB, 0, 0, 0);        \
    _Pragma("unroll") for (int kf = 0; kf < 4; ++kf)                              \
        aA = __builtin_amdgcn_mfma_f32_16x16x32_bf16(af[kf], wh[kf], aA, 0, 0, 0);\
    _Pragma("unroll") for (int kf = 4; kf < 8; ++kf)                              \
        aB = __builtin_amdgcn_mfma_f32_16x16x32_bf16(af[kf], wh[kf], aB, 0, 0, 0);\
    { /* prefetch ef for TT+1, xi for TT+2 */                                     \
      const unsigned short* ep = &s_emb[xi_n * EPAD + 8 * g];                     \
      ef0 = *(const bf16x8*)ep;                                                   \
      ef1 = *(const bf16x8*)(ep + 32);                                            \
      int tn = ((TT) + 2 < Lv) ? (TT) + 2 : (Lv - 1);                             \
      xi_n = s_x[tn * ROWS + lm];                                                 \
    }                                                                             \
    float hv0 = fast_tanh(aA[0] + aB[0]), hv1 = fast_tanh(aA[1] + aB[1]);         \
    float hv2 = fast_tanh(aA[2] + aB[2]), hv3 = fast_tanh(aA[3] + aB[3]);         \
    unsigned p01 = cvtpk_bf16(hv0, hv1), p23 = cvtpk_bf16(hv2, hv3);              \
    wa[0][WBe] = (unsigned short)p01;                                             \
    wa[1][WBe] = (unsigned short)(p01 >> 16);                                     \
    wa[2][WBe] = (unsigned short)p23;                                             \
    wa[3][WBe] = (unsigned short)(p23 >> 16);                                     \
    if (LAST) {                                                                   \
      float* fo = out + HOFF + (size_t)(r0 + 4 * g) * Hv + n;                     \
      fo[0 * Hv] = hv0; fo[1 * Hv] = hv1; fo[2 * Hv] = hv2; fo[3 * Hv] = hv3;     \
    }                                                                             \
    step_barrier();                                                               \
  } while (0)

  STEP(0, HB, 0, 0, 0);  // h_{-1}(buf1) -> h_0(buf0)
  for (int t = 1; t < Lv - 1; t += 2) {
    STEP(t, 0, HB, 1, 0);      // reads h_{t-1}(buf0), exports it
    STEP(t + 1, HB, 0, 1, 0);  // reads h_t(buf1), exports it
  }
  STEP(Lv - 1, 0, HB, 1, 1);  // h_1023 -> buf1, final hidden fp32

  {  // epilogue: export h_1023 (buf1) -> hs[1023]
    u32x2 ev = *(const u32x2*)(ea + HB);
    *(u32x2*)hp = ev;
  }
#undef STEP
}

// Deferred logits: out[b][t][v] = hs[b? t][..]@W_ho + b_ho, full chip.
// Grid 1024: (256 t-groups of 4) x (4 b-groups of 64). 8 waves: wave =
// (vgroup 0..1)x(btile 0..3); per wave 16b x 48v per t.
__global__ __launch_bounds__(512, 2) void logits_gemm(
    const unsigned short* __restrict__ hs, const float* __restrict__ W_ho,
    const float* __restrict__ b_ho, float* __restrict__ out) {
  const int tid = threadIdx.x;
  const int w = tid >> 6, ln = tid & 63, lm = ln & 15, g = ln >> 4;
  const int tg = blockIdx.x >> 2, bg = blockIdx.x & 3;

  // W_ho as B-frags: [vt 0..5][kf 0..7][lane][8 elems] bf16
  __shared__ __attribute__((aligned(16))) unsigned short s_who[3072 * 8];
  for (int f = tid; f < 3072; f += 512) {
    int vt = f >> 9, kf = (f >> 6) & 7, lane = f & 63;
    int k0 = 32 * kf + 8 * (lane >> 4), v = 16 * vt + (lane & 15);
    bf16x8 fr;
#pragma unroll
    for (int i = 0; i < 8; ++i) fr[i] = (short)f2b(W_ho[(k0 + i) * Vv + v]);
    *(bf16x8*)&s_who[f * 8] = fr;
  }
  __syncthreads();

  const int bt = w & 3, vg = w >> 2;
  const int b0 = bg * 64 + bt * 16;
  const int j0 = vg * 3;
  float bb[3];
#pragma unroll
  for (int jj = 0; jj < 3; ++jj) bb[jj] = b_ho[16 * (j0 + jj) + lm];

#pragma unroll
  for (int tt = 0; tt < 4; ++tt) {
    const int t = tg * 4 + tt;
    const unsigned short* hpb = hs + (size_t)t * (256 * 256) + (b0 + lm) * 256 + 8 * g;
    f32x4 acc[3];
#pragma unroll
    for (int jj = 0; jj < 3; ++jj) acc[jj] = (f32x4){bb[jj], bb[jj], bb[jj], bb[jj]};
#pragma unroll
    for (int kf = 0; kf < 8; ++kf) {
      bf16x8 af = *(const bf16x8*)(hpb + 32 * kf);
#pragma unroll
      for (int jj = 0; jj < 3; ++jj) {
        bf16x8 bw = *(const bf16x8*)&s_who[(((j0 + jj) * 8 + kf) * 64 + ln) * 8];
        acc[jj] = __builtin_amdgcn_mfma_f32_16x16x32_bf16(af, bw, acc[jj], 0, 0, 0);
      }
    }
#pragma unroll
    for (int jj = 0; jj < 3; ++jj)
#pragma unroll
      for (int rr = 0; rr < 4; ++rr)
        out[(size_t)(b0 + 4 * g + rr) * (Lv * Vv) + (size_t)t * Vv +
            16 * (j0 + jj) + lm] = acc[jj][rr];
  }
}

// ===================== fallback (R2 kernel, ws too small) =====================
__global__ __launch_bounds__(512, 2) void rnn8(
    const int* __restrict__ x, const float* __restrict__ h0,
    const float* __restrict__ emb, const float* __restrict__ W_ih,
    const float* __restrict__ b_ih, const float* __restrict__ W_ho,
    const float* __restrict__ b_ho, float* __restrict__ out,
    const int* __restrict__ flagp) {
  const int tid = threadIdx.x;
  const int w = tid >> 6, ln = tid & 63, lm = ln & 15, g = ln >> 4;
  const int r0 = blockIdx.x * ROWS;

  __shared__ __attribute__((aligned(16))) unsigned short s_emb[Vv * EPAD];
  __shared__ __attribute__((aligned(16))) unsigned short s_h[2 * HB];
  __shared__ unsigned char s_x[Lv * ROWS];

  const int flag = *flagp;

  for (int idx = tid; idx < Vv * Ev; idx += 512)
    s_emb[(idx >> 6) * EPAD + (idx & 63)] = f2b(emb[idx]);
  for (int idx = tid; idx < ROWS * Hv; idx += 512) {
    int m = idx >> 8, nn = idx & 255;
    s_h[HB + (m << 8) + ((((nn >> 3) ^ (m & 7)) << 3) | (nn & 7))] =
        f2b(h0[(r0 + m) * Hv + nn]);
  }
  for (int idx = tid; idx < ROWS * Lv; idx += 512) {
    int row = idx >> 10, t = idx & 1023;
    long long src = (long long)(r0 + row) * Lv + t;
    int v = flag ? x[2 * src] : x[src];
    s_x[t * ROWS + row] = (unsigned char)v;
  }

  bf16x8 wh[2][8], wx[2][2], who[8];
  float bih[2], bhov = 0.0f;
#pragma unroll
  for (int nt = 0; nt < 2; ++nt) {
    const int n = 32 * w + 16 * nt + lm;
    bih[nt] = b_ih[n];
#pragma unroll
    for (int kf = 0; kf < 8; ++kf)
#pragma unroll
      for (int i = 0; i < 8; ++i)
        wh[nt][kf][i] = (short)f2b(W_ih[(Ev + 32 * kf + 8 * g + i) * Hv + n]);
#pragma unroll
    for (int kf = 0; kf < 2; ++kf)
#pragma unroll
      for (int i = 0; i < 8; ++i)
        wx[nt][kf][i] = (short)f2b(W_ih[(32 * kf + 8 * g + i) * Hv + n]);
  }
  if (w < 6) {
    const int n = 16 * w + lm;
    bhov = b_ho[n];
#pragma unroll
    for (int kf = 0; kf < 8; ++kf)
#pragma unroll
      for (int i = 0; i < 8; ++i)
        who[kf][i] = (short)f2b(W_ho[(32 * kf + 8 * g + i) * Vv + n]);
  }

  const unsigned short* ra[8];
#pragma unroll
  for (int kf = 0; kf < 8; ++kf)
    ra[kf] = &s_h[(lm << 8) + (((4 * kf + g) ^ (lm & 7)) << 3)];
  unsigned short* wa[8];
#pragma unroll
  for (int nt = 0; nt < 2; ++nt)
#pragma unroll
    for (int rr = 0; rr < 4; ++rr) {
      int m = 4 * g + rr, n = 32 * w + 16 * nt + lm;
      wa[nt * 4 + rr] = &s_h[(m << 8) + ((((n >> 3) ^ (m & 7)) << 3) | (n & 7))];
    }
  float* ob[4] = {out, out, out, out};
  if (w < 6) {
#pragma unroll
    for (int rr = 0; rr < 4; ++rr)
      ob[rr] = out + (size_t)(r0 + 4 * g + rr) * (Lv * Vv) + 16 * w + lm;
  }

  __syncthreads();

  bf16x8 ef0, ef1;
  {
    int xi = s_x[lm];
    const unsigned short* ep = &s_emb[xi * EPAD + 8 * g];
    ef0 = *(const bf16x8*)ep;
    ef1 = *(const bf16x8*)(ep + 32);
  }

#define STEP8(TT, RB, WB, DOLOG, LAST)                                             \
  do {                                                                             \
    bf16x8 af[8];                                                                  \
    _Pragma("unroll") for (int kf = 0; kf < 8; ++kf)                               \
        af[kf] = *(const bf16x8*)(ra[kf] + (RB));                                  \
    f32x4 a0 = {bih[0], bih[0], bih[0], bih[0]};                                   \
    f32x4 a1 = {bih[1], bih[1], bih[1], bih[1]};                                   \
    a0 = __builtin_amdgcn_mfma_f32_16x16x32_bf16(ef0, wx[0][0], a0, 0, 0, 0);      \
    a1 = __builtin_amdgcn_mfma_f32_16x16x32_bf16(ef0, wx[1][0], a1, 0, 0, 0);      \
    a0 = __builtin_amdgcn_mfma_f32_16x16x32_bf16(ef1, wx[0][1], a0, 0, 0, 0);      \
    a1 = __builtin_amdgcn_mfma_f32_16x16x32_bf16(ef1, wx[1][1], a1, 0, 0, 0);      \
    _Pragma("unroll") for (int kf = 0; kf < 8; ++kf) {                             \
      a0 = __builtin_amdgcn_mfma_f32_16x16x32_bf16(af[kf], wh[0][kf], a0, 0, 0, 0);\
      a1 = __builtin_amdgcn_mfma_f32_16x16x32_bf16(af[kf], wh[1][kf], a1, 0, 0, 0);\
    }                                                                              \
    if ((DOLOG) && w < 6) {                                                        \
      f32x4 l = {bhov, bhov, bhov, bhov};                                          \
      _Pragma("unroll") for (int kf = 0; kf < 8; ++kf)                             \
          l = __builtin_amdgcn_mfma_f32_16x16x32_bf16(af[kf], who[kf], l, 0, 0, 0);\
      const size_t o = (size_t)((TT)-1) * Vv;                                      \
      ob[0][o] = l[0]; ob[1][o] = l[1]; ob[2][o] = l[2]; ob[3][o] = l[3];          \
    }                                                                              \
    {                                                                              \
      int tn = ((TT) + 1 < Lv) ? (TT) + 1 : (Lv - 1);                              \
      int xi = s_x[tn * ROWS + lm];                                                \
      const unsigned short* ep = &s_emb[xi * EPAD + 8 * g];                        \
      ef0 = *(const bf16x8*)ep;                                                    \
      ef1 = *(const bf16x8*)(ep + 32);                                             \
    }                                                                              \
    float th0 = fast_tanh(a0[0]), th1 = fast_tanh(a0[1]);                          \
    float th2 = fast_tanh(a0[2]), th3 = fast_tanh(a0[3]);                          \
    float th4 = fast_tanh(a1[0]), th5 = fast_tanh(a1[1]);                          \
    float th6 = fast_tanh(a1[2]), th7 = fast_tanh(a1[3]);                          \
    unsigned p01 = cvtpk_bf16(th0, th1), p23 = cvtpk_bf16(th2, th3);               \
    unsigned p45 = cvtpk_bf16(th4, th5), p67 = cvtpk_bf16(th6, th7);               \
    wa[0][WB] = (unsigned short)p01;                                               \
    wa[1][WB] = (unsigned short)(p01 >> 16);                                       \
    wa[2][WB] = (unsigned short)p23;                                               \
    wa[3][WB] = (unsigned short)(p23 >> 16);                                       \
    wa[4][WB] = (unsigned short)p45;                                               \
    wa[5][WB] = (unsigned short)(p45 >> 16);                                       \
    wa[6][WB] = (unsigned short)p67;                                               \
    wa[7][WB] = (unsigned short)(p67 >> 16);                                       \
    if (LAST) {                                                                    \
      float* fh = out + HOFF + (size_t)(r0 + 4 * g) * Hv + 32 * w + lm;            \
      fh[0 * Hv] = th0; fh[1 * Hv] = th1; fh[2 * Hv] = th2; fh[3 * Hv] = th3;      \
      fh[0 * Hv + 16] = th4; fh[1 * Hv + 16] = th5;                                \
      fh[2 * Hv + 16] = th6; fh[3 * Hv + 16] = th7;                                \
    }                                                                              \
    asm volatile("s_waitcnt lgkmcnt(0)\n\ts_barrier" ::: "memory");                \
    __builtin_amdgcn_sched_barrier(0);                                             \
  } while (0)

  STEP8(0, HB, 0, 0, 0);
  for (int t = 1; t < Lv - 1; t += 2) {
    STEP8(t, 0, HB, 1, 0);
    STEP8(t + 1, HB, 0, 1, 0);
  }
  STEP8(Lv - 1, 0, HB, 1, 1);

  if (w < 6) {
    bf16x8 af[8];
#pragma unroll
    for (int kf = 0; kf < 8; ++kf) af[kf] = *(const bf16x8*)(ra[kf] + HB);
    f32x4 l = {bhov, bhov, bhov, bhov};
#pragma unroll
    for (int kf = 0; kf < 8; ++kf)
      l = __builtin_amdgcn_mfma_f32_16x16x32_bf16(af[kf], who[kf], l, 0, 0, 0);
    const size_t o = (size_t)(Lv - 1) * Vv;
    ob[0][o] = l[0]; ob[1][o] = l[1]; ob[2][o] = l[2]; ob[3][o] = l[3];
  }
#undef STEP8
}

extern "C" void kernel_launch(void* const* d_in, const int* in_sizes, int n_in,
                              void* d_out, int out_size, void* d_ws, size_t ws_size,
                              hipStream_t stream) {
  const int* x     = (const int*)d_in[0];
  const float* h0  = (const float*)d_in[1];
  const float* emb = (const float*)d_in[2];
  const float* Wih = (const float*)d_in[3];
  const float* bih = (const float*)d_in[4];
  const float* Who = (const float*)d_in[5];
  const float* bho = (const float*)d_in[6];
  float* out = (float*)d_out;
  int* flag = (int*)d_ws;

  const size_t hs_bytes = (size_t)Lv * 256 * 256 * 2;  // 134.2 MB
  detect_i64<<<1, 64, 0, stream>>>(x, flag);
  if (ws_size >= hs_bytes + 256) {
    unsigned short* hsp = (unsigned short*)((char*)d_ws + 256);
    rnn16<<<16, 1024, 0, stream>>>(x, h0, emb, Wih, bih, out, hsp, flag);
    logits_gemm<<<1024, 512, 0, stream>>>(hsp, Who, bho, out);
  } else {
    rnn8<<<16, 512, 0, stream>>>(x, h0, emb, Wih, bih, Who, bho, out, flag);
  }
}

// Round 5
// 714.776 us; speedup vs baseline: 1.5367x; 1.2471x over previous
//
#include <hip/hip_runtime.h>
#include <hip/hip_bf16.h>

#define Lv 1024
#define Vv 96
#define Ev 64
#define Hv 256
#define ROWS 16
#define HOFF (256 * 1024 * 96)
#define EPAD 72
#define HB 4096  // ushorts per h buffer (16 batch rows x 256 hidden)

typedef __attribute__((ext_vector_type(8))) short bf16x8;
typedef __attribute__((ext_vector_type(4))) float f32x4;
typedef __attribute__((ext_vector_type(2))) unsigned int u32x2;

__device__ __forceinline__ unsigned short f2b(float f) {
  unsigned u = __builtin_bit_cast(unsigned, f);
  return (unsigned short)((u + 0x7fffu + ((u >> 16) & 1u)) >> 16);  // RNE
}
__device__ __forceinline__ unsigned cvtpk_bf16(float lo, float hi) {
  unsigned r;
  asm("v_cvt_pk_bf16_f32 %0, %1, %2" : "=v"(r) : "v"(lo), "v"(hi));
  return r;
}
__device__ __forceinline__ float fast_tanh(float x) {
  float e = __builtin_amdgcn_exp2f(x * 2.885390081777927f);  // exp(2x)
  return 1.0f - 2.0f * __builtin_amdgcn_rcpf(e + 1.0f);
}
// lgkm-only barrier: LDS ordered, global stores keep draining across steps.
__device__ __forceinline__ void step_barrier() {
  asm volatile("s_waitcnt lgkmcnt(0)\n\ts_barrier" ::: "memory");
  __builtin_amdgcn_sched_barrier(0);
}

__global__ void detect_i64(const int* __restrict__ x, int* __restrict__ flag) {
  if (threadIdx.x == 0 && blockIdx.x == 0) {
    int ok = 1;
    for (int i = 0; i < 64; ++i) ok &= (x[2 * i + 1] == 0);
    *flag = ok;
  }
}

// ============================ primary loop =============================
// Transposed recurrence: h_t^T = tanh(Wh^T·h^T + Wx^T·emb^T + b).
// 16 WGs x 16 batch cols, 8 waves (512 thr, 2 waves/SIMD). Wave w owns
// hidden rows [32w,32w+32) (A = weights in regs). D lanes hold 4 consecutive
// hidden per batch col -> b64 LDS writes + register-direct hs export.
// Logits deferred to full-chip GEMM over hs[t][b][h] (bf16).
__global__ __launch_bounds__(512, 2) void rnn8t(
    const int* __restrict__ x, const float* __restrict__ h0,
    const float* __restrict__ emb, const float* __restrict__ W_ih,
    const float* __restrict__ b_ih, float* __restrict__ out,
    unsigned short* __restrict__ hs, const int* __restrict__ flagp) {
  const int tid = threadIdx.x;
  const int w = tid >> 6, ln = tid & 63, lm = ln & 15, g = ln >> 4;
  const int r0 = blockIdx.x * ROWS;

  __shared__ __attribute__((aligned(16))) unsigned short s_h[2 * HB];
  __shared__ __attribute__((aligned(16))) unsigned short s_emb[Vv * EPAD];
  __shared__ unsigned char s_x[Lv * ROWS];

  const int flag = *flagp;  // 1 => x is int64

  for (int idx = tid; idx < Vv * Ev; idx += 512)
    s_emb[(idx >> 6) * EPAD + (idx & 63)] = f2b(emb[idx]);
  for (int idx = tid; idx < ROWS * Hv; idx += 512) {  // h_{-1} -> buf1
    int b_ = idx >> 8, hd = idx & 255;
    s_h[HB + b_ * 256 + ((((hd >> 3) ^ (b_ & 7)) << 3) | (hd & 7))] =
        f2b(h0[(r0 + b_) * Hv + hd]);
  }
  for (int idx = tid; idx < ROWS * Lv; idx += 512) {  // x, transposed u8
    int t = idx >> 4, row = idx & 15;
    long long src = (long long)(r0 + row) * Lv + t;
    int v = flag ? x[2 * src] : x[src];
    s_x[t * ROWS + row] = (unsigned char)v;
  }

  // ---- register-resident weights (A-frags: row=lm, k=8g+i) ----
  bf16x8 wh[2][8], wx[2][2];
  f32x4 bihv[2];
#pragma unroll
  for (int nt = 0; nt < 2; ++nt) {
    const int n = 32 * w + 16 * nt + lm;  // output hidden row
#pragma unroll
    for (int kf = 0; kf < 8; ++kf)
#pragma unroll
      for (int i = 0; i < 8; ++i)
        wh[nt][kf][i] = (short)f2b(W_ih[(Ev + 32 * kf + 8 * g + i) * Hv + n]);
#pragma unroll
    for (int kf = 0; kf < 2; ++kf)
#pragma unroll
      for (int i = 0; i < 8; ++i)
        wx[nt][kf][i] = (short)f2b(W_ih[(32 * kf + 8 * g + i) * Hv + n]);
    bihv[nt] = *(const f32x4*)&b_ih[32 * w + 16 * nt + 4 * g];
  }

  // ---- loop-invariant addresses ----
  const unsigned short* ra[8];  // B-frag reads: batch col = lm, k = 32kf+8g+i
#pragma unroll
  for (int kf = 0; kf < 8; ++kf)
    ra[kf] = &s_h[lm * 256 + (((4 * kf + g) ^ (lm & 7)) << 3)];
  unsigned short* wa[2];  // b64 writes: hidden base hb = 32w+16nt+4g, batch lm
#pragma unroll
  for (int nt = 0; nt < 2; ++nt)
    wa[nt] = &s_h[lm * 256 + (((4 * w + 2 * nt + (g >> 1)) ^ (lm & 7)) << 3) +
                  ((g & 1) << 2)];
  // hs export: hs[t][b][h], 4 bf16 per lane per nt
  unsigned short* hp = hs + (size_t)(r0 + lm) * 0 /*placeholder*/;
  hp = hs + (size_t)(r0 + lm) * 256 + 32 * w + 4 * g;  // t=0, nt=0 slot

  __syncthreads();

  bf16x8 ef0, ef1;  // emb B-frags: col=lm (batch), k=8g+i / 32+8g+i
  int xi_n;
  {
    int xi0 = s_x[lm];
    const unsigned short* ep = &s_emb[xi0 * EPAD + 8 * g];
    ef0 = *(const bf16x8*)ep;
    ef1 = *(const bf16x8*)(ep + 32);
    xi_n = s_x[ROWS + lm];  // t=1
  }

#define STEP(TT, RB, WB, LAST)                                                    \
  do {                                                                            \
    bf16x8 af[8];                                                                 \
    _Pragma("unroll") for (int kf = 0; kf < 8; ++kf)                              \
        af[kf] = *(const bf16x8*)(ra[kf] + (RB));                                 \
    f32x4 aA0 = bihv[0], aA1 = bihv[1];                                           \
    f32x4 aB0 = {0.f, 0.f, 0.f, 0.f}, aB1 = {0.f, 0.f, 0.f, 0.f};                 \
    aA0 = __builtin_amdgcn_mfma_f32_16x16x32_bf16(wx[0][0], ef0, aA0, 0, 0, 0);   \
    aA1 = __builtin_amdgcn_mfma_f32_16x16x32_bf16(wx[1][0], ef0, aA1, 0, 0, 0);   \
    aB0 = __builtin_amdgcn_mfma_f32_16x16x32_bf16(wx[0][1], ef1, aB0, 0, 0, 0);   \
    aB1 = __builtin_amdgcn_mfma_f32_16x16x32_bf16(wx[1][1], ef1, aB1, 0, 0, 0);   \
    _Pragma("unroll") for (int kf = 0; kf < 4; ++kf) {                            \
      aA0 = __builtin_amdgcn_mfma_f32_16x16x32_bf16(wh[0][kf], af[kf], aA0, 0, 0, 0); \
      aA1 = __builtin_amdgcn_mfma_f32_16x16x32_bf16(wh[1][kf], af[kf], aA1, 0, 0, 0); \
    }                                                                             \
    _Pragma("unroll") for (int kf = 4; kf < 8; ++kf) {                            \
      aB0 = __builtin_amdgcn_mfma_f32_16x16x32_bf16(wh[0][kf], af[kf], aB0, 0, 0, 0); \
      aB1 = __builtin_amdgcn_mfma_f32_16x16x32_bf16(wh[1][kf], af[kf], aB1, 0, 0, 0); \
    }                                                                             \
    { /* prefetch ef for TT+1, xi for TT+2 */                                     \
      const unsigned short* ep = &s_emb[xi_n * EPAD + 8 * g];                     \
      ef0 = *(const bf16x8*)ep;                                                   \
      ef1 = *(const bf16x8*)(ep + 32);                                            \
      int tn = ((TT) + 2 < Lv) ? (TT) + 2 : (Lv - 1);                             \
      xi_n = s_x[tn * ROWS + lm];                                                 \
    }                                                                             \
    float h0v = fast_tanh(aA0[0] + aB0[0]), h1v = fast_tanh(aA0[1] + aB0[1]);     \
    float h2v = fast_tanh(aA0[2] + aB0[2]), h3v = fast_tanh(aA0[3] + aB0[3]);     \
    float h4v = fast_tanh(aA1[0] + aB1[0]), h5v = fast_tanh(aA1[1] + aB1[1]);     \
    float h6v = fast_tanh(aA1[2] + aB1[2]), h7v = fast_tanh(aA1[3] + aB1[3]);     \
    u32x2 p0, p1;                                                                 \
    p0[0] = cvtpk_bf16(h0v, h1v);                                                 \
    p0[1] = cvtpk_bf16(h2v, h3v);                                                 \
    p1[0] = cvtpk_bf16(h4v, h5v);                                                 \
    p1[1] = cvtpk_bf16(h6v, h7v);                                                 \
    *(u32x2*)(wa[0] + (WB)) = p0;                                                 \
    *(u32x2*)(wa[1] + (WB)) = p1;                                                 \
    *(u32x2*)hp = p0;        /* hs[TT], nt=0 */                                   \
    *(u32x2*)(hp + 16) = p1; /* hs[TT], nt=1 */                                   \
    hp += 256 * 256;                                                              \
    if (LAST) {                                                                   \
      float* fo = out + HOFF + (size_t)(r0 + lm) * Hv + 32 * w + 4 * g;           \
      *(f32x4*)fo = (f32x4){h0v, h1v, h2v, h3v};                                  \
      *(f32x4*)(fo + 16) = (f32x4){h4v, h5v, h6v, h7v};                           \
    }                                                                             \
    step_barrier();                                                               \
  } while (0)

  STEP(0, HB, 0, 0);  // h_{-1}(buf1) -> h_0(buf0), export hs[0]
  for (int t = 1; t < Lv - 1; t += 2) {
    STEP(t, 0, HB, 0);
    STEP(t + 1, HB, 0, 0);
  }
  STEP(Lv - 1, 0, HB, 1);  // h_1023, export hs[1023], final hidden fp32
#undef STEP
}

// Deferred logits: out[b][t][v] = hs[t][b][:]@W_ho + b_ho, full chip.
// Grid 1024: (256 t-groups of 4) x (4 b-groups of 64). 8 waves: wave =
// (vgroup 0..1)x(btile 0..3); per wave 16b x 48v per t.
__global__ __launch_bounds__(512, 2) void logits_gemm(
    const unsigned short* __restrict__ hs, const float* __restrict__ W_ho,
    const float* __restrict__ b_ho, float* __restrict__ out) {
  const int tid = threadIdx.x;
  const int w = tid >> 6, ln = tid & 63, lm = ln & 15, g = ln >> 4;
  const int tg = blockIdx.x >> 2, bg = blockIdx.x & 3;

  // W_ho as B-frags: [vt 0..5][kf 0..7][lane][8 elems] bf16
  __shared__ __attribute__((aligned(16))) unsigned short s_who[3072 * 8];
  for (int f = tid; f < 3072; f += 512) {
    int vt = f >> 9, kf = (f >> 6) & 7, lane = f & 63;
    int k0 = 32 * kf + 8 * (lane >> 4), v = 16 * vt + (lane & 15);
    bf16x8 fr;
#pragma unroll
    for (int i = 0; i < 8; ++i) fr[i] = (short)f2b(W_ho[(k0 + i) * Vv + v]);
    *(bf16x8*)&s_who[f * 8] = fr;
  }
  __syncthreads();

  const int bt = w & 3, vg = w >> 2;
  const int b0 = bg * 64 + bt * 16;
  const int j0 = vg * 3;
  float bb[3];
#pragma unroll
  for (int jj = 0; jj < 3; ++jj) bb[jj] = b_ho[16 * (j0 + jj) + lm];

#pragma unroll
  for (int tt = 0; tt < 4; ++tt) {
    const int t = tg * 4 + tt;
    const unsigned short* hpb =
        hs + (size_t)t * (256 * 256) + (b0 + lm) * 256 + 8 * g;
    f32x4 acc[3];
#pragma unroll
    for (int jj = 0; jj < 3; ++jj)
      acc[jj] = (f32x4){bb[jj], bb[jj], bb[jj], bb[jj]};
#pragma unroll
    for (int kf = 0; kf < 8; ++kf) {
      bf16x8 af = *(const bf16x8*)(hpb + 32 * kf);
#pragma unroll
      for (int jj = 0; jj < 3; ++jj) {
        bf16x8 bw = *(const bf16x8*)&s_who[(((j0 + jj) * 8 + kf) * 64 + ln) * 8];
        acc[jj] =
            __builtin_amdgcn_mfma_f32_16x16x32_bf16(af, bw, acc[jj], 0, 0, 0);
      }
    }
#pragma unroll
    for (int jj = 0; jj < 3; ++jj)
#pragma unroll
      for (int rr = 0; rr < 4; ++rr)
        out[(size_t)(b0 + 4 * g + rr) * (Lv * Vv) + (size_t)t * Vv +
            16 * (j0 + jj) + lm] = acc[jj][rr];
  }
}

// ===================== fallback (R2 kernel, ws too small) =====================
__global__ __launch_bounds__(512, 2) void rnn8(
    const int* __restrict__ x, const float* __restrict__ h0,
    const float* __restrict__ emb, const float* __restrict__ W_ih,
    const float* __restrict__ b_ih, const float* __restrict__ W_ho,
    const float* __restrict__ b_ho, float* __restrict__ out,
    const int* __restrict__ flagp) {
  const int tid = threadIdx.x;
  const int w = tid >> 6, ln = tid & 63, lm = ln & 15, g = ln >> 4;
  const int r0 = blockIdx.x * ROWS;

  __shared__ __attribute__((aligned(16))) unsigned short s_emb[Vv * EPAD];
  __shared__ __attribute__((aligned(16))) unsigned short s_h[2 * HB];
  __shared__ unsigned char s_x[Lv * ROWS];

  const int flag = *flagp;

  for (int idx = tid; idx < Vv * Ev; idx += 512)
    s_emb[(idx >> 6) * EPAD + (idx & 63)] = f2b(emb[idx]);
  for (int idx = tid; idx < ROWS * Hv; idx += 512) {
    int m = idx >> 8, nn = idx & 255;
    s_h[HB + (m << 8) + ((((nn >> 3) ^ (m & 7)) << 3) | (nn & 7))] =
        f2b(h0[(r0 + m) * Hv + nn]);
  }
  for (int idx = tid; idx < ROWS * Lv; idx += 512) {
    int row = idx >> 10, t = idx & 1023;
    long long src = (long long)(r0 + row) * Lv + t;
    int v = flag ? x[2 * src] : x[src];
    s_x[t * ROWS + row] = (unsigned char)v;
  }

  bf16x8 wh[2][8], wx[2][2], who[8];
  float bih[2], bhov = 0.0f;
#pragma unroll
  for (int nt = 0; nt < 2; ++nt) {
    const int n = 32 * w + 16 * nt + lm;
    bih[nt] = b_ih[n];
#pragma unroll
    for (int kf = 0; kf < 8; ++kf)
#pragma unroll
      for (int i = 0; i < 8; ++i)
        wh[nt][kf][i] = (short)f2b(W_ih[(Ev + 32 * kf + 8 * g + i) * Hv + n]);
#pragma unroll
    for (int kf = 0; kf < 2; ++kf)
#pragma unroll
      for (int i = 0; i < 8; ++i)
        wx[nt][kf][i] = (short)f2b(W_ih[(32 * kf + 8 * g + i) * Hv + n]);
  }
  if (w < 6) {
    const int n = 16 * w + lm;
    bhov = b_ho[n];
#pragma unroll
    for (int kf = 0; kf < 8; ++kf)
#pragma unroll
      for (int i = 0; i < 8; ++i)
        who[kf][i] = (short)f2b(W_ho[(32 * kf + 8 * g + i) * Vv + n]);
  }

  const unsigned short* ra[8];
#pragma unroll
  for (int kf = 0; kf < 8; ++kf)
    ra[kf] = &s_h[(lm << 8) + (((4 * kf + g) ^ (lm & 7)) << 3)];
  unsigned short* wa[8];
#pragma unroll
  for (int nt = 0; nt < 2; ++nt)
#pragma unroll
    for (int rr = 0; rr < 4; ++rr) {
      int m = 4 * g + rr, n = 32 * w + 16 * nt + lm;
      wa[nt * 4 + rr] = &s_h[(m << 8) + ((((n >> 3) ^ (m & 7)) << 3) | (n & 7))];
    }
  float* ob[4] = {out, out, out, out};
  if (w < 6) {
#pragma unroll
    for (int rr = 0; rr < 4; ++rr)
      ob[rr] = out + (size_t)(r0 + 4 * g + rr) * (Lv * Vv) + 16 * w + lm;
  }

  __syncthreads();

  bf16x8 ef0, ef1;
  {
    int xi = s_x[lm];
    const unsigned short* ep = &s_emb[xi * EPAD + 8 * g];
    ef0 = *(const bf16x8*)ep;
    ef1 = *(const bf16x8*)(ep + 32);
  }

#define STEP8(TT, RB, WB, DOLOG, LAST)                                             \
  do {                                                                             \
    bf16x8 af[8];                                                                  \
    _Pragma("unroll") for (int kf = 0; kf < 8; ++kf)                               \
        af[kf] = *(const bf16x8*)(ra[kf] + (RB));                                  \
    f32x4 a0 = {bih[0], bih[0], bih[0], bih[0]};                                   \
    f32x4 a1 = {bih[1], bih[1], bih[1], bih[1]};                                   \
    a0 = __builtin_amdgcn_mfma_f32_16x16x32_bf16(ef0, wx[0][0], a0, 0, 0, 0);      \
    a1 = __builtin_amdgcn_mfma_f32_16x16x32_bf16(ef0, wx[1][0], a1, 0, 0, 0);      \
    a0 = __builtin_amdgcn_mfma_f32_16x16x32_bf16(ef1, wx[0][1], a0, 0, 0, 0);      \
    a1 = __builtin_amdgcn_mfma_f32_16x16x32_bf16(ef1, wx[1][1], a1, 0, 0, 0);      \
    _Pragma("unroll") for (int kf = 0; kf < 8; ++kf) {                             \
      a0 = __builtin_amdgcn_mfma_f32_16x16x32_bf16(af[kf], wh[0][kf], a0, 0, 0, 0);\
      a1 = __builtin_amdgcn_mfma_f32_16x16x32_bf16(af[kf], wh[1][kf], a1, 0, 0, 0);\
    }                                                                              \
    if ((DOLOG) && w < 6) {                                                        \
      f32x4 l = {bhov, bhov, bhov, bhov};                                          \
      _Pragma("unroll") for (int kf = 0; kf < 8; ++kf)                             \
          l = __builtin_amdgcn_mfma_f32_16x16x32_bf16(af[kf], who[kf], l, 0, 0, 0);\
      const size_t o = (size_t)((TT)-1) * Vv;                                      \
      ob[0][o] = l[0]; ob[1][o] = l[1]; ob[2][o] = l[2]; ob[3][o] = l[3];          \
    }                                                                              \
    {                                                                              \
      int tn = ((TT) + 1 < Lv) ? (TT) + 1 : (Lv - 1);                              \
      int xi = s_x[tn * ROWS + lm];                                                \
      const unsigned short* ep = &s_emb[xi * EPAD + 8 * g];                        \
      ef0 = *(const bf16x8*)ep;                                                    \
      ef1 = *(const bf16x8*)(ep + 32);                                             \
    }                                                                              \
    float th0 = fast_tanh(a0[0]), th1 = fast_tanh(a0[1]);                          \
    float th2 = fast_tanh(a0[2]), th3 = fast_tanh(a0[3]);                          \
    float th4 = fast_tanh(a1[0]), th5 = fast_tanh(a1[1]);                          \
    float th6 = fast_tanh(a1[2]), th7 = fast_tanh(a1[3]);                          \
    unsigned p01 = cvtpk_bf16(th0, th1), p23 = cvtpk_bf16(th2, th3);               \
    unsigned p45 = cvtpk_bf16(th4, th5), p67 = cvtpk_bf16(th6, th7);               \
    wa[0][WB] = (unsigned short)p01;                                               \
    wa[1][WB] = (unsigned short)(p01 >> 16);                                       \
    wa[2][WB] = (unsigned short)p23;                                               \
    wa[3][WB] = (unsigned short)(p23 >> 16);                                       \
    wa[4][WB] = (unsigned short)p45;                                               \
    wa[5][WB] = (unsigned short)(p45 >> 16);                                       \
    wa[6][WB] = (unsigned short)p67;                                               \
    wa[7][WB] = (unsigned short)(p67 >> 16);                                       \
    if (LAST) {                                                                    \
      float* fh = out + HOFF + (size_t)(r0 + 4 * g) * Hv + 32 * w + lm;            \
      fh[0 * Hv] = th0; fh[1 * Hv] = th1; fh[2 * Hv] = th2; fh[3 * Hv] = th3;      \
      fh[0 * Hv + 16] = th4; fh[1 * Hv + 16] = th5;                                \
      fh[2 * Hv + 16] = th6; fh[3 * Hv + 16] = th7;                                \
    }                                                                              \
    asm volatile("s_waitcnt lgkmcnt(0)\n\ts_barrier" ::: "memory");                \
    __builtin_amdgcn_sched_barrier(0);                                             \
  } while (0)

  STEP8(0, HB, 0, 0, 0);
  for (int t = 1; t < Lv - 1; t += 2) {
    STEP8(t, 0, HB, 1, 0);
    STEP8(t + 1, HB, 0, 1, 0);
  }
  STEP8(Lv - 1, 0, HB, 1, 1);

  if (w < 6) {
    bf16x8 af[8];
#pragma unroll
    for (int kf = 0; kf < 8; ++kf) af[kf] = *(const bf16x8*)(ra[kf] + HB);
    f32x4 l = {bhov, bhov, bhov, bhov};
#pragma unroll
    for (int kf = 0; kf < 8; ++kf)
      l = __builtin_amdgcn_mfma_f32_16x16x32_bf16(af[kf], who[kf], l, 0, 0, 0);
    const size_t o = (size_t)(Lv - 1) * Vv;
    ob[0][o] = l[0]; ob[1][o] = l[1]; ob[2][o] = l[2]; ob[3][o] = l[3];
  }
#undef STEP8
}

extern "C" void kernel_launch(void* const* d_in, const int* in_sizes, int n_in,
                              void* d_out, int out_size, void* d_ws, size_t ws_size,
                              hipStream_t stream) {
  const int* x     = (const int*)d_in[0];
  const float* h0  = (const float*)d_in[1];
  const float* emb = (const float*)d_in[2];
  const float* Wih = (const float*)d_in[3];
  const float* bih = (const float*)d_in[4];
  const float* Who = (const float*)d_in[5];
  const float* bho = (const float*)d_in[6];
  float* out = (float*)d_out;
  int* flag = (int*)d_ws;

  const size_t hs_bytes = (size_t)Lv * 256 * 256 * 2;  // 134.2 MB
  detect_i64<<<1, 64, 0, stream>>>(x, flag);
  if (ws_size >= hs_bytes + 256) {
    unsigned short* hsp = (unsigned short*)((char*)d_ws + 256);
    rnn8t<<<16, 512, 0, stream>>>(x, h0, emb, Wih, bih, out, hsp, flag);
    logits_gemm<<<1024, 512, 0, stream>>>(hsp, Who, bho, out);
  } else {
    rnn8<<<16, 512, 0, stream>>>(x, h0, emb, Wih, bih, Who, bho, out, flag);
  }
}